// Round 4
// baseline (633.787 us; speedup 1.0000x reference)
//
#include <hip/hip_runtime.h>
#include <math.h>

#define B_ 16
#define NSUP_ 4096
#define NQ_ 4096
#define D_ 512
#define C_ 128
#define MARGIN 0.008f   // f32 screen gap error worst ~2e-4 (qsq cancels); 40x safety

// ============ K1: per-tile histogram + stable within-tile rank ============
// grid 16 (one per batch), 256 threads (4 waves); tile = 64 targets.
__global__ __launch_bounds__(256) void hist_kernel(
    const int* __restrict__ tgt, int* __restrict__ rank, int* __restrict__ tile_hist)
{
    int b = blockIdx.x, tid = threadIdx.x;
    int wave = tid >> 6, lane = tid & 63;
    for (int i = tid; i < 64 * C_; i += 256) tile_hist[b * 64 * C_ + i] = 0;
    __syncthreads();
    for (int tile = wave; tile < 64; tile += 4) {
        int i = b * NSUP_ + tile * 64 + lane;
        int my = tgt[i];
        int before = 0, after = 0;
        for (int s = 0; s < 64; s++) {
            int ts = __shfl(my, s, 64);
            before += (ts == my && s < lane);
            after  += (ts == my && s > lane);
        }
        rank[i] = before;
        if (after == 0) tile_hist[(b * 64 + tile) * C_ + my] = before + 1;  // one lane per class
    }
}

// ============ K2: prefix hist -> tile_base (in place) + class_base/cnt ============
// grid 16, 128 threads (one per class).
__global__ __launch_bounds__(128) void prefix_kernel(
    int* __restrict__ tile_hist, int* __restrict__ class_base, int* __restrict__ class_cnt)
{
    __shared__ int lh[64][C_];      // 32 KB
    __shared__ int scnt[C_];
    __shared__ int cbase[C_];
    int b = blockIdx.x, c = threadIdx.x;
    for (int t = 0; t < 64; t++) lh[t][c] = tile_hist[(b * 64 + t) * C_ + c];
    int run = 0;
    for (int t = 0; t < 64; t++) { int v = lh[t][c]; lh[t][c] = run; run += v; }
    scnt[c] = run;
    __syncthreads();
    if (c == 0) { int s = 0; for (int k = 0; k < C_; k++) { cbase[k] = s; s += scnt[k]; } }
    __syncthreads();
    class_base[b * C_ + c] = cbase[c];
    class_cnt [b * C_ + c] = scnt[c];
    for (int t = 0; t < 64; t++) tile_hist[(b * 64 + t) * C_ + c] = lh[t][c] + cbase[c];
}

// ============ K3: scatter indices into class-grouped permutation ============
// grid 256 x 256 = 65536 threads.
__global__ __launch_bounds__(256) void scatter_kernel(
    const int* __restrict__ tgt, const int* __restrict__ rank,
    const int* __restrict__ tile_base, int* __restrict__ perm,
    int* __restrict__ flag_count, int* __restrict__ acc_delta)
{
    int i = blockIdx.x * 256 + threadIdx.x;
    if (i == 0) { *flag_count = 0; *acc_delta = 0; }
    int b = i >> 12, ii = i & 4095, tile = ii >> 6;
    int c = tgt[i];
    int pos = tile_base[(b * 64 + tile) * C_ + c] + rank[i];
    perm[b * NSUP_ + pos] = ii;
}

// ============ K4: gather-reduce prototypes (f64 regs) ============
// grid B_*C_ = 2048, 256 threads; thread owns dims (2t, 2t+1).
__global__ __launch_bounds__(256) void proto_kernel(
    const float* __restrict__ sup, const int* __restrict__ class_base,
    const int* __restrict__ class_cnt, const int* __restrict__ perm,
    float* __restrict__ pf32, double* __restrict__ p64,
    double* __restrict__ psq64, float* __restrict__ psq32)
{
    __shared__ int rows[256];
    __shared__ double red[256];
    int g = blockIdx.x, b = g >> 7, c = g & 127;
    int tid = threadIdx.x;
    int base = class_base[b * C_ + c], cnt = class_cnt[b * C_ + c];
    const float* eb = sup + (size_t)b * NSUP_ * D_;
    int d = 2 * tid;
    double a0 = 0.0, a1 = 0.0;
    for (int r0 = 0; r0 < cnt; r0 += 256) {
        int nr = min(256, cnt - r0);
        __syncthreads();
        if (tid < nr) rows[tid] = perm[b * NSUP_ + base + r0 + tid];
        __syncthreads();
        for (int r = 0; r < nr; r++) {
            float2 v = *(const float2*)(eb + (size_t)rows[r] * D_ + d);
            a0 += (double)v.x; a1 += (double)v.y;
        }
    }
    double cw = (double)(cnt > 1 ? cnt : 1);
    a0 /= cw; a1 /= cw;
    size_t ob = (size_t)(b * C_ + c) * D_ + d;
    pf32[ob] = (float)a0; pf32[ob + 1] = (float)a1;
    p64[ob] = a0; p64[ob + 1] = a1;
    red[tid] = a0 * a0 + a1 * a1;
    __syncthreads();
    for (int s = 128; s > 0; s >>= 1) {
        if (tid < s) red[tid] += red[tid + s];
        __syncthreads();
    }
    if (tid == 0) { psq64[g] = red[0]; psq32[g] = (float)red[0]; }
}

// ============ K5: f32 screen — q via uniform global reads, p via LDS ============
// grid B_*(NQ_/32) = 2048, 256 threads (4 waves x 8 queries).
// dist_c = ||p_c||^2 - 2<p_c,q>  (qsq dropped: cancels in argmin, gaps, and nll)
__global__ __launch_bounds__(256, 6) void screen_kernel(
    const float* __restrict__ qry, const int* __restrict__ qtgt,
    const float* __restrict__ pf32, const float* __restrict__ psq32,
    float* __restrict__ out_pred, double* __restrict__ blk_loss,
    float* __restrict__ blk_acc, int* __restrict__ flags, int* __restrict__ flag_count)
{
    __shared__ float ldsP[C_][33];   // stride 33: bank = (l+dl)%32 -> 2-way alias (free)
    __shared__ double wl[4];
    __shared__ float  wa[4];

    int blk  = blockIdx.x;
    int b    = blk >> 7;
    int qb   = (blk & 127) * 32;
    int tid  = threadIdx.x;
    int lane = tid & 63;
    int wave = __builtin_amdgcn_readfirstlane(tid >> 6);   // provably uniform
    int q0   = qb + wave * 8;

    const float* pb32 = pf32 + (size_t)b * C_ * D_;

    float acc0[8] = {0,0,0,0,0,0,0,0};
    float acc1[8] = {0,0,0,0,0,0,0,0};

    for (int ch = 0; ch < 16; ch++) {
        __syncthreads();
        {   // stage P chunk: thread t -> class t>>1, 16 cols
            int c = tid >> 1, col0 = (tid & 1) << 4;
            const float* src = pb32 + (size_t)c * D_ + ch * 32 + col0;
            float4 v0 = *(const float4*)(src);
            float4 v1 = *(const float4*)(src + 4);
            float4 v2 = *(const float4*)(src + 8);
            float4 v3 = *(const float4*)(src + 12);
            float* dst = &ldsP[c][col0];
            dst[0]=v0.x; dst[1]=v0.y; dst[2]=v0.z; dst[3]=v0.w;
            dst[4]=v1.x; dst[5]=v1.y; dst[6]=v1.z; dst[7]=v1.w;
            dst[8]=v2.x; dst[9]=v2.y; dst[10]=v2.z; dst[11]=v2.w;
            dst[12]=v3.x; dst[13]=v3.y; dst[14]=v3.z; dst[15]=v3.w;
        }
        __syncthreads();

        const float* qu = qry + ((size_t)b * NQ_ + q0) * D_ + ch * 32;  // wave-uniform
        #pragma unroll
        for (int dl = 0; dl < 32; dl += 4) {
            float p0[4], p1[4];
            #pragma unroll
            for (int k = 0; k < 4; k++) {
                p0[k] = ldsP[lane][dl + k];
                p1[k] = ldsP[lane + 64][dl + k];
            }
            #pragma unroll
            for (int j = 0; j < 8; j++) {
                float4 qv = *(const float4*)(qu + j * D_ + dl);   // uniform -> scalar path
                acc0[j] = fmaf(p0[0], qv.x, acc0[j]);
                acc0[j] = fmaf(p0[1], qv.y, acc0[j]);
                acc0[j] = fmaf(p0[2], qv.z, acc0[j]);
                acc0[j] = fmaf(p0[3], qv.w, acc0[j]);
                acc1[j] = fmaf(p1[0], qv.x, acc1[j]);
                acc1[j] = fmaf(p1[1], qv.y, acc1[j]);
                acc1[j] = fmaf(p1[2], qv.z, acc1[j]);
                acc1[j] = fmaf(p1[3], qv.w, acc1[j]);
            }
        }
    }

    float ps0 = psq32[b * C_ + lane];
    float ps1 = psq32[b * C_ + lane + 64];
    double wloss = 0.0; float wacc = 0.0f;

    for (int j = 0; j < 8; j++) {
        float df0 = ps0 - 2.0f * acc0[j];   // qsq omitted (constant across classes)
        float df1 = ps1 - 2.0f * acc1[j];

        // top-2 butterfly; first-index tie-break
        float b1, b2; int c1;
        if (df1 < df0) { b1 = df1; c1 = lane + 64; b2 = df0; }
        else           { b1 = df0; c1 = lane;      b2 = df1; }
        for (int off = 32; off; off >>= 1) {
            float o1 = __shfl_xor(b1, off, 64);
            int   oc = __shfl_xor(c1, off, 64);
            float o2 = __shfl_xor(b2, off, 64);
            float n2 = fminf(fmaxf(b1, o1), fminf(b2, o2));
            if (o1 < b1 || (o1 == b1 && oc < c1)) { b1 = o1; c1 = oc; }
            b2 = n2;
        }

        // logsumexp of -dist over 128 classes (online max-sub: offset-safe)
        float nd0 = -df0, nd1 = -df1;
        float lm = fmaxf(nd0, nd1);
        float ls = __expf(nd0 - lm) + __expf(nd1 - lm);
        for (int off = 32; off; off >>= 1) {
            float om = __shfl_xor(lm, off, 64);
            float os = __shfl_xor(ls, off, 64);
            float nm = fmaxf(lm, om);
            ls = ls * __expf(lm - nm) + os * __expf(om - nm);
            lm = nm;
        }

        int tq = qtgt[b * NQ_ + q0 + j];
        float cand = (tq & 64) ? df1 : df0;
        float dt = __shfl(cand, tq & 63, 64);
        wloss += (double)(dt + lm) + (double)logf(ls);
        wacc  += (c1 == tq) ? 1.0f : 0.0f;

        if (lane == 0) {
            int gq = b * NQ_ + q0 + j;
            out_pred[gq] = (float)c1;
            if (b2 - b1 < MARGIN) {
                int pos = atomicAdd(flag_count, 1);
                flags[pos] = gq;
            }
        }
    }

    if (lane == 0) { wl[wave] = wloss; wa[wave] = wacc; }
    __syncthreads();
    if (tid == 0) {
        blk_loss[blk] = wl[0] + wl[1] + wl[2] + wl[3];
        blk_acc[blk]  = wa[0] + wa[1] + wa[2] + wa[3];
    }
}

// ============ K6: exact f64 rescue, wave-per-query ============
// lane owns dims [8l, 8l+8); coalesced 4KB p64 row reads; 2-class ILP.
__global__ __launch_bounds__(256) void rescue_kernel(
    const float* __restrict__ qry, const int* __restrict__ qtgt,
    const double* __restrict__ p64, const double* __restrict__ psq64,
    const int* __restrict__ flags, const int* __restrict__ flag_count,
    float* __restrict__ out_pred, int* __restrict__ acc_delta)
{
    int tid = threadIdx.x, wave = tid >> 6, lane = tid & 63;
    int cnt = *flag_count;
    for (int f = blockIdx.x * 4 + wave; f < cnt; f += 1024) {
        int gq = flags[f];
        int b  = gq >> 12;
        const float* qp = qry + (size_t)gq * D_;
        float4 qa = *(const float4*)(qp + 8 * lane);
        float4 qb4 = *(const float4*)(qp + 8 * lane + 4);
        double q[8] = {(double)qa.x,(double)qa.y,(double)qa.z,(double)qa.w,
                       (double)qb4.x,(double)qb4.y,(double)qb4.z,(double)qb4.w};
        double qsq = 0.0;
        #pragma unroll
        for (int k = 0; k < 8; k++) qsq = fma(q[k], q[k], qsq);
        for (int off = 32; off; off >>= 1) qsq += __shfl_xor(qsq, off, 64);

        const double* pb = p64 + (size_t)b * C_ * D_;
        double bd = 1e300; int bc = 0;
        for (int c = 0; c < C_; c += 2) {
            const double* pr0 = pb + (size_t)c * D_ + 8 * lane;
            const double* pr1 = pr0 + D_;
            double dot0 = 0.0, dot1 = 0.0;
            #pragma unroll
            for (int k = 0; k < 8; k++) {
                dot0 = fma(pr0[k], q[k], dot0);
                dot1 = fma(pr1[k], q[k], dot1);
            }
            for (int off = 32; off; off >>= 1) {
                dot0 += __shfl_xor(dot0, off, 64);
                dot1 += __shfl_xor(dot1, off, 64);
            }
            double d0 = psq64[b * C_ + c]     + qsq - 2.0 * dot0;
            double d1 = psq64[b * C_ + c + 1] + qsq - 2.0 * dot1;
            if (d0 < bd) { bd = d0; bc = c; }       // ascending + strict < = first min
            if (d1 < bd) { bd = d1; bc = c + 1; }
        }
        if (lane == 0) {
            int tq = qtgt[gq];
            int oldc = (int)out_pred[gq];
            if (oldc != bc) {
                out_pred[gq] = (float)bc;
                int delta = ((bc == tq) ? 1 : 0) - ((oldc == tq) ? 1 : 0);
                if (delta) atomicAdd(acc_delta, delta);
            }
        }
    }
}

// ============ K7: finalize ============
__global__ __launch_bounds__(256) void finalize_kernel(
    const double* __restrict__ blk_loss, const float* __restrict__ blk_acc,
    const int* __restrict__ acc_delta, float* __restrict__ out)
{
    __shared__ double rl[256];
    __shared__ float  ra[256];
    int tid = threadIdx.x;
    double s = 0.0; float a = 0.0f;
    for (int i = tid; i < 2048; i += 256) { s += blk_loss[i]; a += blk_acc[i]; }
    rl[tid] = s; ra[tid] = a;
    __syncthreads();
    for (int st = 128; st; st >>= 1) {
        if (tid < st) { rl[tid] += rl[tid + st]; ra[tid] += ra[tid + st]; }
        __syncthreads();
    }
    if (tid == 0) {
        out[B_*NQ_    ] = (float)(rl[0] / (double)(B_ * NQ_));
        out[B_*NQ_ + 1] = (ra[0] + (float)(*acc_delta)) / (float)(B_ * NQ_);
    }
}

extern "C" void kernel_launch(void* const* d_in, const int* in_sizes, int n_in,
                              void* d_out, int out_size, void* d_ws, size_t ws_size,
                              hipStream_t stream) {
    const float* sup  = (const float*)d_in[0];
    const float* qry  = (const float*)d_in[1];
    const int*   stgt = (const int*)d_in[2];
    const int*   qtgt = (const int*)d_in[3];
    float* out = (float*)d_out;

    char* ws = (char*)d_ws;
    constexpr size_t O_P64   = 0;                    // 8 MiB
    constexpr size_t O_PF32  = O_P64   + 8388608;    // 4 MiB
    constexpr size_t O_PSQ64 = O_PF32  + 4194304;    // 16 KiB
    constexpr size_t O_PSQ32 = O_PSQ64 + 16384;      // 8 KiB
    constexpr size_t O_RANK  = O_PSQ32 + 8192;       // 256 KiB
    constexpr size_t O_HIST  = O_RANK  + 262144;     // 512 KiB
    constexpr size_t O_CBASE = O_HIST  + 524288;     // 8 KiB
    constexpr size_t O_CCNT  = O_CBASE + 8192;       // 8 KiB
    constexpr size_t O_PERM  = O_CCNT  + 8192;       // 256 KiB
    constexpr size_t O_BLOSS = O_PERM  + 262144;     // 16 KiB
    constexpr size_t O_BACC  = O_BLOSS + 16384;      // 8 KiB
    constexpr size_t O_FLAGS = O_BACC  + 8192;       // 256 KiB
    constexpr size_t O_CNT   = O_FLAGS + 262144;

    double* p64       = (double*)(ws + O_P64);
    float*  pf32      = (float*) (ws + O_PF32);
    double* psq64     = (double*)(ws + O_PSQ64);
    float*  psq32     = (float*) (ws + O_PSQ32);
    int*    rank      = (int*)   (ws + O_RANK);
    int*    tile_hist = (int*)   (ws + O_HIST);
    int*    cbase     = (int*)   (ws + O_CBASE);
    int*    ccnt      = (int*)   (ws + O_CCNT);
    int*    perm      = (int*)   (ws + O_PERM);
    double* blk_loss  = (double*)(ws + O_BLOSS);
    float*  blk_acc   = (float*) (ws + O_BACC);
    int*    flags     = (int*)   (ws + O_FLAGS);
    int*    flag_count= (int*)   (ws + O_CNT);
    int*    acc_delta = flag_count + 1;

    hipLaunchKernelGGL(hist_kernel,    dim3(16),   dim3(256), 0, stream, stgt, rank, tile_hist);
    hipLaunchKernelGGL(prefix_kernel,  dim3(16),   dim3(128), 0, stream, tile_hist, cbase, ccnt);
    hipLaunchKernelGGL(scatter_kernel, dim3(256),  dim3(256), 0, stream,
                       stgt, rank, tile_hist, perm, flag_count, acc_delta);
    hipLaunchKernelGGL(proto_kernel,   dim3(2048), dim3(256), 0, stream,
                       sup, cbase, ccnt, perm, pf32, p64, psq64, psq32);
    hipLaunchKernelGGL(screen_kernel,  dim3(2048), dim3(256), 0, stream,
                       qry, qtgt, pf32, psq32, out, blk_loss, blk_acc, flags, flag_count);
    hipLaunchKernelGGL(rescue_kernel,  dim3(256),  dim3(256), 0, stream,
                       qry, qtgt, p64, psq64, flags, flag_count, out, acc_delta);
    hipLaunchKernelGGL(finalize_kernel, dim3(1),   dim3(256), 0, stream,
                       blk_loss, blk_acc, acc_delta, out);
}

// Round 5
// 396.233 us; speedup vs baseline: 1.5995x; 1.5995x over previous
//
#include <hip/hip_runtime.h>
#include <math.h>

#define B_ 16
#define NSUP_ 4096
#define NQ_ 4096
#define D_ 512
#define C_ 128
#define MARGIN 0.02f   // bf16-split dist err worst ~2e-3; 10x safety

typedef __attribute__((ext_vector_type(8))) short bf16x8;
typedef __attribute__((ext_vector_type(4))) float f32x4;

__device__ inline short f2bf(float f) {   // RNE f32 -> bf16 bits
    unsigned u = __float_as_uint(f);
    unsigned r = (u + 0x7fffu + ((u >> 16) & 1u)) >> 16;
    return (short)r;
}
__device__ inline float bf2f(short h) {
    return __uint_as_float(((unsigned)(unsigned short)h) << 16);
}

// ============ K1: per-batch LDS counting sort (unstable; order-invariance OK) ============
// grid 16, 256 threads.
__global__ __launch_bounds__(256) void sort_kernel(
    const int* __restrict__ tgt, int* __restrict__ perm,
    int* __restrict__ class_base, int* __restrict__ class_cnt,
    int* __restrict__ flag_count, int* __restrict__ acc_delta)
{
    __shared__ int cnt[C_];
    __shared__ int base[C_];
    int b = blockIdx.x, tid = threadIdx.x;
    if (tid < C_) cnt[tid] = 0;
    __syncthreads();
    for (int i = tid; i < NSUP_; i += 256) atomicAdd(&cnt[tgt[b * NSUP_ + i]], 1);
    __syncthreads();
    if (tid == 0) { int s = 0; for (int c = 0; c < C_; c++) { base[c] = s; s += cnt[c]; } }
    __syncthreads();
    if (tid < C_) {
        class_base[b * C_ + tid] = base[tid];
        class_cnt [b * C_ + tid] = cnt[tid];
    }
    if (b == 0 && tid == 0) { *flag_count = 0; *acc_delta = 0; }
    __syncthreads();
    for (int i = tid; i < NSUP_; i += 256) {
        int c = tgt[b * NSUP_ + i];
        int pos = atomicAdd(&base[c], 1);
        perm[b * NSUP_ + pos] = i;
    }
}

// ============ K2: gather-reduce prototypes (f64 regs), sup read exactly once ============
// grid B_*C_ = 2048, 256 threads; thread owns dims (2t, 2t+1).
__global__ __launch_bounds__(256) void proto_kernel(
    const float* __restrict__ sup, const int* __restrict__ class_base,
    const int* __restrict__ class_cnt, const int* __restrict__ perm,
    float* __restrict__ pf32, double* __restrict__ p64,
    double* __restrict__ psq64, float* __restrict__ psq32)
{
    __shared__ int rows[256];
    __shared__ double red[256];
    int g = blockIdx.x, b = g >> 7, c = g & 127;
    int tid = threadIdx.x;
    int base = class_base[b * C_ + c], cnt = class_cnt[b * C_ + c];
    const float* eb = sup + (size_t)b * NSUP_ * D_;
    int d = 2 * tid;
    double a0 = 0.0, a1 = 0.0;
    for (int r0 = 0; r0 < cnt; r0 += 256) {
        int nr = min(256, cnt - r0);
        __syncthreads();
        if (tid < nr) rows[tid] = perm[b * NSUP_ + base + r0 + tid];
        __syncthreads();
        for (int r = 0; r < nr; r++) {
            float2 v = *(const float2*)(eb + (size_t)rows[r] * D_ + d);
            a0 += (double)v.x; a1 += (double)v.y;
        }
    }
    double cw = (double)(cnt > 1 ? cnt : 1);
    a0 /= cw; a1 /= cw;
    size_t ob = (size_t)(b * C_ + c) * D_ + d;
    pf32[ob] = (float)a0; pf32[ob + 1] = (float)a1;
    p64[ob] = a0; p64[ob + 1] = a1;
    red[tid] = a0 * a0 + a1 * a1;
    __syncthreads();
    for (int s = 128; s > 0; s >>= 1) {
        if (tid < s) red[tid] += red[tid + s];
        __syncthreads();
    }
    if (tid == 0) { psq64[g] = red[0]; psq32[g] = (float)red[0]; }
}

// ============ K3: MFMA bf16-split screen ============
// grid 16 batches x 32 qtiles = 512 blocks, 256 threads (4 waves).
// Block: 128 classes x 128 queries, K=512 in 8 chunks of 64.
// Wave: all 8 mtiles x 2 ntiles (32 queries), acc = 16 C-frags.
__global__ __launch_bounds__(256) void screen_kernel(
    const float* __restrict__ qry, const int* __restrict__ qtgt,
    const float* __restrict__ pf32, const float* __restrict__ psq32,
    float* __restrict__ out_pred, double* __restrict__ blk_loss,
    float* __restrict__ blk_acc, int* __restrict__ flags, int* __restrict__ flag_count)
{
    __shared__ __align__(16) short Ah[C_ * 64];   // 16 KB each
    __shared__ __align__(16) short Al[C_ * 64];
    __shared__ __align__(16) short Bh[128 * 64];
    __shared__ __align__(16) short Bl[128 * 64];
    __shared__ float ldsPsq[C_];
    __shared__ double wl[4];
    __shared__ float  wa[4];

    int blk = blockIdx.x;
    int b   = blk >> 5;
    int qb  = (blk & 31) * 128;
    int tid = threadIdx.x;
    int wave = tid >> 6, lane = tid & 63;
    int quad = lane >> 4, n16 = lane & 15;

    if (tid < C_) ldsPsq[tid] = psq32[b * C_ + tid];

    f32x4 acc[8][2];
    #pragma unroll
    for (int mt = 0; mt < 8; mt++)
        #pragma unroll
        for (int nt = 0; nt < 2; nt++)
            acc[mt][nt] = (f32x4){0.f, 0.f, 0.f, 0.f};

    const float* pb = pf32 + (size_t)b * C_ * D_;
    const float* qbB = qry + ((size_t)b * NQ_ + qb) * D_;

    for (int ch = 0; ch < 8; ch++) {
        __syncthreads();
        // ---- stage A (protos) : 1024 tasks (row c, 8-k group) ----
        #pragma unroll
        for (int it = 0; it < 4; it++) {
            int t2 = tid + 256 * it;
            int c = t2 >> 3, grp = t2 & 7;
            const float* src = pb + (size_t)c * D_ + ch * 64 + grp * 8;
            float4 f0 = *(const float4*)(src);
            float4 f1 = *(const float4*)(src + 4);
            float xv[8] = {f0.x, f0.y, f0.z, f0.w, f1.x, f1.y, f1.z, f1.w};
            bf16x8 h8, l8;
            #pragma unroll
            for (int e = 0; e < 8; e++) {
                short hb = f2bf(xv[e]);
                h8[e] = hb;
                l8[e] = f2bf(xv[e] - bf2f(hb));
            }
            int tile2 = ((c >> 4) << 1) + (grp >> 2);
            int lp = ((grp & 3) << 4) + (c & 15);
            int addr = (tile2 * 64 + lp) * 8;
            *(bf16x8*)&Ah[addr] = h8;
            *(bf16x8*)&Al[addr] = l8;
        }
        // ---- stage B (queries) ----
        #pragma unroll
        for (int it = 0; it < 4; it++) {
            int t2 = tid + 256 * it;
            int q = t2 >> 3, grp = t2 & 7;
            const float* src = qbB + (size_t)q * D_ + ch * 64 + grp * 8;
            float4 f0 = *(const float4*)(src);
            float4 f1 = *(const float4*)(src + 4);
            float xv[8] = {f0.x, f0.y, f0.z, f0.w, f1.x, f1.y, f1.z, f1.w};
            bf16x8 h8, l8;
            #pragma unroll
            for (int e = 0; e < 8; e++) {
                short hb = f2bf(xv[e]);
                h8[e] = hb;
                l8[e] = f2bf(xv[e] - bf2f(hb));
            }
            int tile2 = ((q >> 4) << 1) + (grp >> 2);
            int lp = ((grp & 3) << 4) + (q & 15);
            int addr = (tile2 * 64 + lp) * 8;
            *(bf16x8*)&Bh[addr] = h8;
            *(bf16x8*)&Bl[addr] = l8;
        }
        __syncthreads();

        int nt0 = wave * 2, nt1 = wave * 2 + 1;
        #pragma unroll
        for (int ks = 0; ks < 2; ks++) {
            bf16x8 bh0 = *(const bf16x8*)&Bh[((nt0 * 2 + ks) * 64 + lane) * 8];
            bf16x8 bl0 = *(const bf16x8*)&Bl[((nt0 * 2 + ks) * 64 + lane) * 8];
            bf16x8 bh1 = *(const bf16x8*)&Bh[((nt1 * 2 + ks) * 64 + lane) * 8];
            bf16x8 bl1 = *(const bf16x8*)&Bl[((nt1 * 2 + ks) * 64 + lane) * 8];
            #pragma unroll
            for (int mt = 0; mt < 8; mt++) {
                bf16x8 ah = *(const bf16x8*)&Ah[((mt * 2 + ks) * 64 + lane) * 8];
                bf16x8 al = *(const bf16x8*)&Al[((mt * 2 + ks) * 64 + lane) * 8];
                acc[mt][0] = __builtin_amdgcn_mfma_f32_16x16x32_bf16(ah, bh0, acc[mt][0], 0, 0, 0);
                acc[mt][0] = __builtin_amdgcn_mfma_f32_16x16x32_bf16(ah, bl0, acc[mt][0], 0, 0, 0);
                acc[mt][0] = __builtin_amdgcn_mfma_f32_16x16x32_bf16(al, bh0, acc[mt][0], 0, 0, 0);
                acc[mt][1] = __builtin_amdgcn_mfma_f32_16x16x32_bf16(ah, bh1, acc[mt][1], 0, 0, 0);
                acc[mt][1] = __builtin_amdgcn_mfma_f32_16x16x32_bf16(ah, bl1, acc[mt][1], 0, 0, 0);
                acc[mt][1] = __builtin_amdgcn_mfma_f32_16x16x32_bf16(al, bh1, acc[mt][1], 0, 0, 0);
            }
        }
    }

    // ---- epilogue: dist = psq - 2*dot; per-query top2/lse/nll over C/D layout ----
    // C/D: col(query) = lane&15, row(class) = mt*16 + quad*4 + reg
    float4 psqv[8];
    #pragma unroll
    for (int mt = 0; mt < 8; mt++)
        psqv[mt] = *(const float4*)&ldsPsq[mt * 16 + quad * 4];

    double wloss = 0.0; float wacc = 0.0f;

    #pragma unroll
    for (int nt = 0; nt < 2; nt++) {
        int ntg = wave * 2 + nt;
        int qloc = ntg * 16 + n16;
        int gq = b * NQ_ + qb + qloc;
        int tq = qtgt[gq];

        float b1 = 1e30f, b2 = 1e30f, dt = 1e30f, lm = -1e30f;
        int c1 = 0;
        #pragma unroll
        for (int mt = 0; mt < 8; mt++) {
            #pragma unroll
            for (int r = 0; r < 4; r++) {
                float d = psqv[mt][r] - 2.0f * acc[mt][nt][r];
                int c = mt * 16 + quad * 4 + r;
                if (d < b1) { b2 = b1; b1 = d; c1 = c; }
                else if (d < b2) { b2 = d; }
                lm = fmaxf(lm, -d);
                if (c == tq) dt = d;
            }
        }
        float ls = 0.0f;
        #pragma unroll
        for (int mt = 0; mt < 8; mt++) {
            #pragma unroll
            for (int r = 0; r < 4; r++) {
                float d = psqv[mt][r] - 2.0f * acc[mt][nt][r];
                ls += __expf(-d - lm);
            }
        }
        // reduce across the 4 lanes holding this query (xor 16, 32)
        #pragma unroll
        for (int off = 16; off <= 32; off <<= 1) {
            float o1 = __shfl_xor(b1, off, 64);
            int   oc = __shfl_xor(c1, off, 64);
            float o2 = __shfl_xor(b2, off, 64);
            float n2 = fminf(fmaxf(b1, o1), fminf(b2, o2));
            if (o1 < b1 || (o1 == b1 && oc < c1)) { b1 = o1; c1 = oc; }
            b2 = n2;
            float om = __shfl_xor(lm, off, 64);
            float os = __shfl_xor(ls, off, 64);
            float nm = fmaxf(lm, om);
            ls = ls * __expf(lm - nm) + os * __expf(om - nm);
            lm = nm;
            dt = fminf(dt, __shfl_xor(dt, off, 64));
        }
        if (quad == 0) {
            wloss += (double)(dt + lm) + (double)logf(ls);
            wacc  += (c1 == tq) ? 1.0f : 0.0f;
            out_pred[gq] = (float)c1;
            if (b2 - b1 < MARGIN) {
                int pos = atomicAdd(flag_count, 1);
                flags[pos] = gq;
            }
        }
    }

    // wave reduce (contributions live in lanes 0..15 only)
    #pragma unroll
    for (int off = 1; off <= 8; off <<= 1) {
        wloss += __shfl_xor(wloss, off, 64);
        wacc  += __shfl_xor(wacc,  off, 64);
    }
    if (lane == 0) { wl[wave] = wloss; wa[wave] = wacc; }
    __syncthreads();
    if (tid == 0) {
        blk_loss[blk] = wl[0] + wl[1] + wl[2] + wl[3];
        blk_acc[blk]  = wa[0] + wa[1] + wa[2] + wa[3];
    }
}

// ============ K4: exact f64 rescue, wave-per-query ============
__global__ __launch_bounds__(256) void rescue_kernel(
    const float* __restrict__ qry, const int* __restrict__ qtgt,
    const double* __restrict__ p64, const double* __restrict__ psq64,
    const int* __restrict__ flags, const int* __restrict__ flag_count,
    float* __restrict__ out_pred, int* __restrict__ acc_delta)
{
    int tid = threadIdx.x, wave = tid >> 6, lane = tid & 63;
    int cnt = *flag_count;
    for (int f = blockIdx.x * 4 + wave; f < cnt; f += 1024) {
        int gq = flags[f];
        int b  = gq >> 12;
        const float* qp = qry + (size_t)gq * D_;
        float4 qa = *(const float4*)(qp + 8 * lane);
        float4 qb4 = *(const float4*)(qp + 8 * lane + 4);
        double q[8] = {(double)qa.x,(double)qa.y,(double)qa.z,(double)qa.w,
                       (double)qb4.x,(double)qb4.y,(double)qb4.z,(double)qb4.w};
        double qsq = 0.0;
        #pragma unroll
        for (int k = 0; k < 8; k++) qsq = fma(q[k], q[k], qsq);
        for (int off = 32; off; off >>= 1) qsq += __shfl_xor(qsq, off, 64);

        const double* pb = p64 + (size_t)b * C_ * D_;
        double bd = 1e300; int bc = 0;
        for (int c = 0; c < C_; c += 2) {
            const double* pr0 = pb + (size_t)c * D_ + 8 * lane;
            const double* pr1 = pr0 + D_;
            double dot0 = 0.0, dot1 = 0.0;
            #pragma unroll
            for (int k = 0; k < 8; k++) {
                dot0 = fma(pr0[k], q[k], dot0);
                dot1 = fma(pr1[k], q[k], dot1);
            }
            for (int off = 32; off; off >>= 1) {
                dot0 += __shfl_xor(dot0, off, 64);
                dot1 += __shfl_xor(dot1, off, 64);
            }
            double d0 = psq64[b * C_ + c]     + qsq - 2.0 * dot0;
            double d1 = psq64[b * C_ + c + 1] + qsq - 2.0 * dot1;
            if (d0 < bd) { bd = d0; bc = c; }
            if (d1 < bd) { bd = d1; bc = c + 1; }
        }
        if (lane == 0) {
            int tq = qtgt[gq];
            int oldc = (int)out_pred[gq];
            if (oldc != bc) {
                out_pred[gq] = (float)bc;
                int delta = ((bc == tq) ? 1 : 0) - ((oldc == tq) ? 1 : 0);
                if (delta) atomicAdd(acc_delta, delta);
            }
        }
    }
}

// ============ K5: finalize ============
__global__ __launch_bounds__(256) void finalize_kernel(
    const double* __restrict__ blk_loss, const float* __restrict__ blk_acc,
    const int* __restrict__ acc_delta, float* __restrict__ out)
{
    __shared__ double rl[256];
    __shared__ float  ra[256];
    int tid = threadIdx.x;
    double s = 0.0; float a = 0.0f;
    for (int i = tid; i < 512; i += 256) { s += blk_loss[i]; a += blk_acc[i]; }
    rl[tid] = s; ra[tid] = a;
    __syncthreads();
    for (int st = 128; st; st >>= 1) {
        if (tid < st) { rl[tid] += rl[tid + st]; ra[tid] += ra[tid + st]; }
        __syncthreads();
    }
    if (tid == 0) {
        out[B_*NQ_    ] = (float)(rl[0] / (double)(B_ * NQ_));
        out[B_*NQ_ + 1] = (ra[0] + (float)(*acc_delta)) / (float)(B_ * NQ_);
    }
}

extern "C" void kernel_launch(void* const* d_in, const int* in_sizes, int n_in,
                              void* d_out, int out_size, void* d_ws, size_t ws_size,
                              hipStream_t stream) {
    const float* sup  = (const float*)d_in[0];
    const float* qry  = (const float*)d_in[1];
    const int*   stgt = (const int*)d_in[2];
    const int*   qtgt = (const int*)d_in[3];
    float* out = (float*)d_out;

    char* ws = (char*)d_ws;
    constexpr size_t O_P64   = 0;                    // 8 MiB
    constexpr size_t O_PF32  = O_P64   + 8388608;    // 4 MiB
    constexpr size_t O_PSQ64 = O_PF32  + 4194304;    // 16 KiB
    constexpr size_t O_PSQ32 = O_PSQ64 + 16384;      // 8 KiB
    constexpr size_t O_CBASE = O_PSQ32 + 8192;       // 8 KiB
    constexpr size_t O_CCNT  = O_CBASE + 8192;       // 8 KiB
    constexpr size_t O_PERM  = O_CCNT  + 8192;       // 256 KiB
    constexpr size_t O_BLOSS = O_PERM  + 262144;     // 4 KiB (512 blocks)
    constexpr size_t O_BACC  = O_BLOSS + 4096;       // 2 KiB
    constexpr size_t O_FLAGS = O_BACC  + 2048;       // 256 KiB
    constexpr size_t O_CNT   = O_FLAGS + 262144;

    double* p64       = (double*)(ws + O_P64);
    float*  pf32      = (float*) (ws + O_PF32);
    double* psq64     = (double*)(ws + O_PSQ64);
    float*  psq32     = (float*) (ws + O_PSQ32);
    int*    cbase     = (int*)   (ws + O_CBASE);
    int*    ccnt      = (int*)   (ws + O_CCNT);
    int*    perm      = (int*)   (ws + O_PERM);
    double* blk_loss  = (double*)(ws + O_BLOSS);
    float*  blk_acc   = (float*) (ws + O_BACC);
    int*    flags     = (int*)   (ws + O_FLAGS);
    int*    flag_count= (int*)   (ws + O_CNT);
    int*    acc_delta = flag_count + 1;

    hipLaunchKernelGGL(sort_kernel,   dim3(16),   dim3(256), 0, stream,
                       stgt, perm, cbase, ccnt, flag_count, acc_delta);
    hipLaunchKernelGGL(proto_kernel,  dim3(2048), dim3(256), 0, stream,
                       sup, cbase, ccnt, perm, pf32, p64, psq64, psq32);
    hipLaunchKernelGGL(screen_kernel, dim3(512),  dim3(256), 0, stream,
                       qry, qtgt, pf32, psq32, out, blk_loss, blk_acc, flags, flag_count);
    hipLaunchKernelGGL(rescue_kernel, dim3(256),  dim3(256), 0, stream,
                       qry, qtgt, p64, psq64, flags, flag_count, out, acc_delta);
    hipLaunchKernelGGL(finalize_kernel, dim3(1),  dim3(256), 0, stream,
                       blk_loss, blk_acc, acc_delta, out);
}